// Round 6
// baseline (433.437 us; speedup 1.0000x reference)
//
#include <hip/hip_runtime.h>
#include <math.h>

#define NLAT 361
#define NLON 720
#define EPSF 1e-7f
#define TWOPI_N 6.283185307179586e+0  // 2*pi; step = TWOPI_N/720

// ---------------------------------------------------------------------------
// Kernel 1: real DFT over longitude, two latitude rows per block (shared
// rotators), fused quadrature weight, output in leg-friendly layout:
//   GG[m][j][bc] = float4( Fp.re, Fp.im, Ft.re, Ft.im ) * (2pi/720) * w[j]
// m = 0..359 (Nyquist bin 360 is dead under the triangular mask).
// Thread m (0..180) produces bins m and 360-m via n-parity routing; per-lane
// incremental complex rotators replace the LDS twiddle table (no bank
// conflicts, no index ALU).
// ---------------------------------------------------------------------------
__global__ void dft_kernel(const float* __restrict__ pred,
                           const float* __restrict__ targ,
                           const float* __restrict__ wq,
                           float4* __restrict__ GG) {
  const int blk = blockIdx.x;          // 16 * 181 blocks
  const int bc  = blk / 181;
  const int p   = blk - bc * 181;
  const int j0  = 2 * p;
  const int j1  = (j0 + 1 <= 360) ? j0 + 1 : j0;   // row 360 pairs with itself

  const float* fp0 = pred + ((size_t)bc * NLAT + j0) * NLON;
  const float* ft0 = targ + ((size_t)bc * NLAT + j0) * NLON;
  const float* fp1 = pred + ((size_t)bc * NLAT + j1) * NLON;
  const float* ft1 = targ + ((size_t)bc * NLAT + j1) * NLON;

  __shared__ float4 eo[2][360];        // (e_p, o_p, e_t, o_t), n=1..359
  const int tid = threadIdx.x;
  for (int idx = tid; idx < 720; idx += 192) {
    int r = idx / 360, n = idx - 360 * r;
    if (n >= 1) {
      const float* a = r ? fp1 : fp0;
      const float* b = r ? ft1 : ft0;
      float a1 = a[n], a2 = a[NLON - n], b1 = b[n], b2 = b[NLON - n];
      eo[r][n] = make_float4(a1 + a2, a1 - a2, b1 + b2, b1 - b2);
    }
  }
  __syncthreads();

  const int m = tid;
  if (m > 180) return;

  // rotators: chain1 at angle (2k-1)*m*t0, chain2 at (2k)*m*t0; step 2m*t0
  float c1, s1, c2, s2, cs, ss;
  {
    float a1 = (float)(TWOPI_N / 720.0 * (double)m);
    float a2 = (float)(TWOPI_N / 720.0 * (double)(2 * m));
    sincosf(a1, &s1, &c1);
    sincosf(a2, &ss, &cs);
    c2 = cs; s2 = ss;
  }

  float CeP0 = 0.f, CoP0 = 0.f, SeP0 = 0.f, SoP0 = 0.f;
  float CeT0 = 0.f, CoT0 = 0.f, SeT0 = 0.f, SoT0 = 0.f;
  float CeP1 = 0.f, CoP1 = 0.f, SeP1 = 0.f, SoP1 = 0.f;
  float CeT1 = 0.f, CoT1 = 0.f, SeT1 = 0.f, SoT1 = 0.f;

#pragma unroll 2
  for (int k = 1; k <= 179; ++k) {
    float4 u0 = eo[0][2 * k - 1], v0 = eo[0][2 * k];
    float4 u1 = eo[1][2 * k - 1], v1 = eo[1][2 * k];
    CoP0 += u0.x * c1; SoP0 += u0.y * s1; CoT0 += u0.z * c1; SoT0 += u0.w * s1;
    CeP0 += v0.x * c2; SeP0 += v0.y * s2; CeT0 += v0.z * c2; SeT0 += v0.w * s2;
    CoP1 += u1.x * c1; SoP1 += u1.y * s1; CoT1 += u1.z * c1; SoT1 += u1.w * s1;
    CeP1 += v1.x * c2; SeP1 += v1.y * s2; CeT1 += v1.z * c2; SeT1 += v1.w * s2;
    float nc1 = c1 * cs - s1 * ss, ns1 = s1 * cs + c1 * ss;
    c1 = nc1; s1 = ns1;
    float nc2 = c2 * cs - s2 * ss, ns2 = s2 * cs + c2 * ss;
    c2 = nc2; s2 = ns2;
  }
  { // tail n = 359 (odd); c1,s1 now at angle 359*m*t0
    float4 u0 = eo[0][359], u1 = eo[1][359];
    CoP0 += u0.x * c1; SoP0 += u0.y * s1; CoT0 += u0.z * c1; SoT0 += u0.w * s1;
    CoP1 += u1.x * c1; SoP1 += u1.y * s1; CoT1 += u1.z * c1; SoT1 += u1.w * s1;
  }

  const float sgn = (m & 1) ? -1.f : 1.f;
  const float t0w = (float)(TWOPI_N / 720.0);
  // row 0
  {
    float baseP = fp0[0] + sgn * fp0[360];
    float baseT = ft0[0] + sgn * ft0[360];
    float sc = t0w * wq[j0];
    float reP = baseP + CeP0 + CoP0, imP = -(SeP0 + SoP0);
    float reT = baseT + CeT0 + CoT0, imT = -(SeT0 + SoT0);
    GG[((size_t)m * NLAT + j0) * 16 + bc] =
        make_float4(reP * sc, imP * sc, reT * sc, imT * sc);
    if (m >= 1 && m <= 179) {
      int m2 = 360 - m;
      float reP2 = baseP + CeP0 - CoP0, imP2 = SeP0 - SoP0;
      float reT2 = baseT + CeT0 - CoT0, imT2 = SeT0 - SoT0;
      GG[((size_t)m2 * NLAT + j0) * 16 + bc] =
          make_float4(reP2 * sc, imP2 * sc, reT2 * sc, imT2 * sc);
    }
  }
  // row 1 (duplicate write when j1==j0 is benign: same thread, same value)
  {
    float baseP = fp1[0] + sgn * fp1[360];
    float baseT = ft1[0] + sgn * ft1[360];
    float sc = t0w * wq[j1];
    float reP = baseP + CeP1 + CoP1, imP = -(SeP1 + SoP1);
    float reT = baseT + CeT1 + CoT1, imT = -(SeT1 + SoT1);
    GG[((size_t)m * NLAT + j1) * 16 + bc] =
        make_float4(reP * sc, imP * sc, reT * sc, imT * sc);
    if (m >= 1 && m <= 179) {
      int m2 = 360 - m;
      float reP2 = baseP + CeP1 - CoP1, imP2 = SeP1 - SoP1;
      float reT2 = baseT + CeT1 - CoT1, imT2 = SeT1 - SoT1;
      GG[((size_t)m2 * NLAT + j1) * 16 + bc] =
          make_float4(reP2 * sc, imP2 * sc, reT2 * sc, imT2 * sc);
    }
  }
}

// ---------------------------------------------------------------------------
// Kernel 2: Legendre contraction + triangular PSD/cross-spectrum.
// Parity symmetry Pbar_lm(-x) = (-1)^(l+m) Pbar_lm(x): only j=0..180 read.
// Block: 256 thr = 16 bc x 4 j-lanes x 4 l-groups; 16 l x 2 m per block;
// grid 2208 (R4). Partials streamed to Spart (R3, no atomics).
//
// R5 changes (evidence: SQ_LDS_BANK_CONFLICT = 4.26M, constant since R0):
//  - sLg stride 20 -> 24 floats: the 16 distinct b128 read addresses per
//    wave now start at banks {0,4,...,28} exactly 2x each -> 2-way = free.
//  - XOR column swizzle (lp ^= ((j>>2)&3)<<2, float4-granular involution):
//    staging writes drop from 8/16-way to 4-way; reads unswizzle for free
//    because (j>>2)&3 is wave-uniform per unrolled instruction.
//  - j=180 center hoisted out of the main loop (jl==0 tail, h0/h1 trick):
//    removes 8 muls + 1 select per iteration (-25% inner-loop VALU).
//  - __launch_bounds__(256,8) guarantees 8 blocks/CU residency
//    (LDS 17.4 KB x 8 = 139 KB < 160 KB; VGPR cap 64, currently 36).
// ---------------------------------------------------------------------------
__global__ __launch_bounds__(256, 8)
void leg_kernel(const float* __restrict__ leg,
                const float4* __restrict__ GG,
                float4* __restrict__ Spart) {
  int bid = blockIdx.x;
  int lt = 0, acc = 0;
  while (bid >= acc + 8 * (lt + 1)) { acc += 8 * (lt + 1); ++lt; }
  const int l0 = lt * 16;
  const int m0 = (bid - acc) * 2;

  __shared__ float sLg[181][24];   // stride 24 floats (96B): b128 reads 2-way
  const int tid = threadIdx.x;
  const int bc  = tid >> 4;        // 0..15  (consecutive bc lanes -> full 64B lines)
  const int jl  = (tid >> 2) & 3;  // 0..3   (xor 4/8 shuffle reduction)
  const int lpg = tid & 3;         // 0..3   (l-group: rows lpg*4 .. lpg*4+3)

  float racc[4][4];
#pragma unroll
  for (int r = 0; r < 4; ++r)
#pragma unroll
    for (int c = 0; c < 4; ++c) racc[r][c] = 0.f;

  for (int mi = 0; mi < 2; ++mi) {
    const int m = m0 + mi;
    if (m > 359) break;            // block-uniform
    if (mi) __syncthreads();
    // stage leg[l0..l0+15][m][0..180] transposed (coalesced global read);
    // column swizzled by ((j>>2)&3)<<2 to spread write banks (4-way max).
    for (int idx = tid; idx < 16 * 181; idx += 256) {
      int lp = idx / 181, j = idx - lp * 181;
      int l = l0 + lp;
      int col = lp ^ (((j >> 2) & 3) << 2);
      sLg[j][col] = (l <= 360) ? leg[((size_t)l * NLAT + m) * NLAT + j] : 0.f;
    }
    __syncthreads();

    // parity of row lpg*4+0: (l0+m)&1. u0 = A + sgn*B serves even sub-rows,
    // u1 = A - sgn*B odd sub-rows.
    const float sgn  = ((l0 + m) & 1) ? -1.f : 1.f;
    const float msgn = -sgn;
    float ca[4][4];
#pragma unroll
    for (int r = 0; r < 4; ++r)
#pragma unroll
      for (int c = 0; c < 4; ++c) ca[r][c] = 0.f;

    const float4* gm = GG + (size_t)m * (NLAT * 16);
#pragma unroll 2
    for (int j = jl; j < 180; j += 4) {
      float4 A = gm[j * 16 + bc];
      float4 B = gm[(360 - j) * 16 + bc];
      float u0x = fmaf(sgn,  B.x, A.x), u0y = fmaf(sgn,  B.y, A.y);
      float u0z = fmaf(sgn,  B.z, A.z), u0w = fmaf(sgn,  B.w, A.w);
      float u1x = fmaf(msgn, B.x, A.x), u1y = fmaf(msgn, B.y, A.y);
      float u1z = fmaf(msgn, B.z, A.z), u1w = fmaf(msgn, B.w, A.w);
      float4 lg = *(const float4*)&sLg[j][(lpg ^ ((j >> 2) & 3)) << 2];
      ca[0][0] += lg.x * u0x; ca[0][1] += lg.x * u0y;
      ca[0][2] += lg.x * u0z; ca[0][3] += lg.x * u0w;
      ca[1][0] += lg.y * u1x; ca[1][1] += lg.y * u1y;
      ca[1][2] += lg.y * u1z; ca[1][3] += lg.y * u1w;
      ca[2][0] += lg.z * u0x; ca[2][1] += lg.z * u0y;
      ca[2][2] += lg.z * u0z; ca[2][3] += lg.z * u0w;
      ca[3][0] += lg.w * u1x; ca[3][1] += lg.w * u1y;
      ca[3][2] += lg.w * u1z; ca[3][3] += lg.w * u1w;
    }
    // center j = 180 (self-paired, half weight): jl==0 lanes only.
    // h0 = 1 if even parity else 0; h1 = complement.
    if (jl == 0) {
      float4 A = gm[180 * 16 + bc];
      const float h0 = 0.5f + 0.5f * sgn;
      const float h1 = 0.5f - 0.5f * sgn;
      float u0x = h0 * A.x, u0y = h0 * A.y, u0z = h0 * A.z, u0w = h0 * A.w;
      float u1x = h1 * A.x, u1y = h1 * A.y, u1z = h1 * A.z, u1w = h1 * A.w;
      // j=180: (j>>2)&3 == 1
      float4 lg = *(const float4*)&sLg[180][(lpg ^ 1) << 2];
      ca[0][0] += lg.x * u0x; ca[0][1] += lg.x * u0y;
      ca[0][2] += lg.x * u0z; ca[0][3] += lg.x * u0w;
      ca[1][0] += lg.y * u1x; ca[1][1] += lg.y * u1y;
      ca[1][2] += lg.y * u1z; ca[1][3] += lg.y * u1w;
      ca[2][0] += lg.z * u0x; ca[2][1] += lg.z * u0y;
      ca[2][2] += lg.z * u0z; ca[2][3] += lg.z * u0w;
      ca[3][0] += lg.w * u1x; ca[3][1] += lg.w * u1y;
      ca[3][2] += lg.w * u1z; ca[3][3] += lg.w * u1w;
    }

    // reduce across the 4 j-lanes (bits 2..3 of lane id)
#pragma unroll
    for (int r = 0; r < 4; ++r)
#pragma unroll
      for (int c = 0; c < 4; ++c) {
        ca[r][c] += __shfl_xor(ca[r][c], 4);
        ca[r][c] += __shfl_xor(ca[r][c], 8);
      }
    const float ef = (m == 0) ? 1.f : 2.f;
#pragma unroll
    for (int r = 0; r < 4; ++r) {
      float pr = ca[r][0], pi = ca[r][1], tr = ca[r][2], ti = ca[r][3];
      racc[r][0] += ef * (pr * pr + pi * pi);
      racc[r][1] += ef * (tr * tr + ti * ti);
      racc[r][2] += ef * (pr * tr + pi * ti);
      racc[r][3] += ef * (pr * ti - pi * tr);
    }
  }

  if (jl == 0) {
    // stream partials: Spart[bid][bc*16 + lrow] = (pp, tp, sr, si)
    float4* sp = Spart + (size_t)blockIdx.x * 256;
#pragma unroll
    for (int r = 0; r < 4; ++r) {
      int lrow = lpg * 4 + r;
      sp[bc * 16 + lrow] =
          make_float4(racc[r][0], racc[r][1], racc[r][2], racc[r][3]);
    }
  }
}

// ---------------------------------------------------------------------------
// Kernel 2b: sum per-block partials into S. 92 blocks (4 per l-tile, one
// thread per output element) + 4 independent accumulators (R4: fixed the
// serial-load-chain latency). nmb = 8*(lt+1) is always divisible by 4.
// ---------------------------------------------------------------------------
__global__ void red_kernel(const float* __restrict__ Spart,
                           float* __restrict__ S) {
  const int b    = blockIdx.x;            // 0..91
  const int lt   = b >> 2;                // 0..22
  const int base = 4 * lt * (lt + 1);     // prefix of 8*(i+1)
  const int nmb  = 8 * (lt + 1);          // m-blocks in this tile
  const int idx  = ((b & 3) << 8) | threadIdx.x;   // 0..1023

  const float* p = Spart + (size_t)base * 1024 + idx;
  float s0 = 0.f, s1 = 0.f, s2 = 0.f, s3 = 0.f;
  for (int mb = 0; mb < nmb; mb += 4) {
    s0 += p[(size_t)(mb + 0) * 1024];
    s1 += p[(size_t)(mb + 1) * 1024];
    s2 += p[(size_t)(mb + 2) * 1024];
    s3 += p[(size_t)(mb + 3) * 1024];
  }
  float s = (s0 + s1) + (s2 + s3);
  int bc = idx >> 6, lrow = (idx >> 2) & 15, c = idx & 3;
  int l = lt * 16 + lrow;
  if (l < 360) S[((size_t)bc * 360 + l) * 4 + c] = s;
}

// ---------------------------------------------------------------------------
// Kernel 3: final loss epilogue + reduction. One block.
// ---------------------------------------------------------------------------
__global__ void loss_kernel(const float* __restrict__ S,
                            const float* __restrict__ wts,
                            float* __restrict__ out) {
  const int tid = threadIdx.x;
  float acc = 0.f;
  for (int i = tid; i < 16 * 360; i += 256) {
    int bc = i / 360;
    const float* sp = S + (size_t)i * 4;
    float pp = sp[0] + EPSF;
    float tp = sp[1] + EPSF;
    float sr = sp[2], si = sp[3];
    float mag   = sqrtf(sr * sr + si * si);
    float denom = sqrtf(pp * tp + EPSF);
    float coh   = mag / (denom + EPSF);
    coh = fminf(fmaxf(coh, 0.f), 1.f);
    float sqp = sqrtf(pp), sqt = sqrtf(tp);
    float amp = (sqp - sqt) * (sqp - sqt);
    float dec = 2.f * fmaxf(pp, tp) * (1.f - coh);
    acc += (amp + dec) * wts[bc & 7];
  }
  __shared__ float red[4];
#pragma unroll
  for (int off = 32; off > 0; off >>= 1) acc += __shfl_xor(acc, off, 64);
  if ((tid & 63) == 0) red[tid >> 6] = acc;
  __syncthreads();
  if (tid == 0) {
    float loss = (red[0] + red[1] + red[2] + red[3]) / (360.f * 16.f);
    out[0] = isnan(loss) ? 1e6f : loss;
  }
}

// ---------------------------------------------------------------------------
extern "C" void kernel_launch(void* const* d_in, const int* in_sizes, int n_in,
                              void* d_out, int out_size, void* d_ws, size_t ws_size,
                              hipStream_t stream) {
  const float* pred = (const float*)d_in[0];   // [2,8,361,720]
  const float* targ = (const float*)d_in[1];   // [2,8,361,720]
  const float* wts  = (const float*)d_in[2];   // [8]
  const float* leg  = (const float*)d_in[3];   // [361,361,361]
  const float* wq   = (const float*)d_in[4];   // [361]
  float* out = (float*)d_out;

  float4* GG    = (float4*)d_ws;                              // [360][361][16] float4
  float*  S     = (float*)(GG + (size_t)360 * NLAT * 16);     // [16][360][4]
  float*  Spart = S + (size_t)16 * 360 * 4;                   // [2208][1024]

  dft_kernel<<<16 * 181, 192, 0, stream>>>(pred, targ, wq, GG);

  // 2208 = sum over 23 l-tiles of 8*(lt+1) two-m blocks
  leg_kernel<<<2208, 256, 0, stream>>>(leg, GG, (float4*)Spart);

  red_kernel<<<92, 256, 0, stream>>>(Spart, S);

  loss_kernel<<<1, 256, 0, stream>>>(S, wts, out);
}

// Round 7
// 430.492 us; speedup vs baseline: 1.0068x; 1.0068x over previous
//
#include <hip/hip_runtime.h>
#include <math.h>

#define NLAT 361
#define NLON 720
#define EPSF 1e-7f
#define TWOPI_N 6.283185307179586e+0  // 2*pi; step = TWOPI_N/720

// ---------------------------------------------------------------------------
// Kernel 1: real DFT over longitude, PARITY-FOLDED output (R7).
// Block handles the latitude pair (p, 360-p) (p=180 self-paired) and emits
//   Gp[m][p][bc] = w0*G(m,p) + w1*G(m,360-p)   (j-symmetric part)
//   Gm[m][p][bc] = w0*G(m,p) - w1*G(m,360-p)   (j-antisymmetric part)
// (w = quadrature weight * 2pi/720; center p=180 pre-halved so Gp[180]=A,
// Gm[180]=0). This hoists leg_kernel's per-iteration u0/u1 fold (8 fmaf per
// lane-iter, ~30% of its inner-loop VALU) into a one-time O(m*j) pass here.
// Same total DFT work and output bytes as before (2*181 rows vs 361).
// ---------------------------------------------------------------------------
__global__ void dft_kernel(const float* __restrict__ pred,
                           const float* __restrict__ targ,
                           const float* __restrict__ wq,
                           float4* __restrict__ Gp,
                           float4* __restrict__ Gm) {
  const int blk = blockIdx.x;          // 16 * 181 blocks
  const int bc  = blk / 181;
  const int p   = blk - bc * 181;      // 0..180
  const int j0  = p;
  const int j1  = 360 - p;             // p=180: j1==j0 (self-paired)

  const float* fp0 = pred + ((size_t)bc * NLAT + j0) * NLON;
  const float* ft0 = targ + ((size_t)bc * NLAT + j0) * NLON;
  const float* fp1 = pred + ((size_t)bc * NLAT + j1) * NLON;
  const float* ft1 = targ + ((size_t)bc * NLAT + j1) * NLON;

  __shared__ float4 eo[2][360];        // (e_p, o_p, e_t, o_t), n=1..359
  const int tid = threadIdx.x;
  for (int idx = tid; idx < 720; idx += 192) {
    int r = idx / 360, n = idx - 360 * r;
    if (n >= 1) {
      const float* a = r ? fp1 : fp0;
      const float* b = r ? ft1 : ft0;
      float a1 = a[n], a2 = a[NLON - n], b1 = b[n], b2 = b[NLON - n];
      eo[r][n] = make_float4(a1 + a2, a1 - a2, b1 + b2, b1 - b2);
    }
  }
  __syncthreads();

  const int m = tid;
  if (m > 180) return;

  // rotators: chain1 at angle (2k-1)*m*t0, chain2 at (2k)*m*t0; step 2m*t0
  float c1, s1, c2, s2, cs, ss;
  {
    float a1 = (float)(TWOPI_N / 720.0 * (double)m);
    float a2 = (float)(TWOPI_N / 720.0 * (double)(2 * m));
    sincosf(a1, &s1, &c1);
    sincosf(a2, &ss, &cs);
    c2 = cs; s2 = ss;
  }

  float CeP0 = 0.f, CoP0 = 0.f, SeP0 = 0.f, SoP0 = 0.f;
  float CeT0 = 0.f, CoT0 = 0.f, SeT0 = 0.f, SoT0 = 0.f;
  float CeP1 = 0.f, CoP1 = 0.f, SeP1 = 0.f, SoP1 = 0.f;
  float CeT1 = 0.f, CoT1 = 0.f, SeT1 = 0.f, SoT1 = 0.f;

#pragma unroll 2
  for (int k = 1; k <= 179; ++k) {
    float4 u0 = eo[0][2 * k - 1], v0 = eo[0][2 * k];
    float4 u1 = eo[1][2 * k - 1], v1 = eo[1][2 * k];
    CoP0 += u0.x * c1; SoP0 += u0.y * s1; CoT0 += u0.z * c1; SoT0 += u0.w * s1;
    CeP0 += v0.x * c2; SeP0 += v0.y * s2; CeT0 += v0.z * c2; SeT0 += v0.w * s2;
    CoP1 += u1.x * c1; SoP1 += u1.y * s1; CoT1 += u1.z * c1; SoT1 += u1.w * s1;
    CeP1 += v1.x * c2; SeP1 += v1.y * s2; CeT1 += v1.z * c2; SeT1 += v1.w * s2;
    float nc1 = c1 * cs - s1 * ss, ns1 = s1 * cs + c1 * ss;
    c1 = nc1; s1 = ns1;
    float nc2 = c2 * cs - s2 * ss, ns2 = s2 * cs + c2 * ss;
    c2 = nc2; s2 = ns2;
  }
  { // tail n = 359 (odd); c1,s1 now at angle 359*m*t0
    float4 u0 = eo[0][359], u1 = eo[1][359];
    CoP0 += u0.x * c1; SoP0 += u0.y * s1; CoT0 += u0.z * c1; SoT0 += u0.w * s1;
    CoP1 += u1.x * c1; SoP1 += u1.y * s1; CoT1 += u1.z * c1; SoT1 += u1.w * s1;
  }

  const float sgn = (m & 1) ? -1.f : 1.f;
  const float t0w = (float)(TWOPI_N / 720.0);
  float sc0 = t0w * wq[j0];
  float sc1 = t0w * wq[j1];
  if (p == 180) { sc0 *= 0.5f; sc1 = sc0; }   // self-paired center: pre-halve

  // row results, weighted
  float baseP0 = fp0[0] + sgn * fp0[360], baseT0 = ft0[0] + sgn * ft0[360];
  float baseP1 = fp1[0] + sgn * fp1[360], baseT1 = ft1[0] + sgn * ft1[360];

  // bin m
  {
    float rP0 = (baseP0 + CeP0 + CoP0) * sc0, iP0 = -(SeP0 + SoP0) * sc0;
    float rT0 = (baseT0 + CeT0 + CoT0) * sc0, iT0 = -(SeT0 + SoT0) * sc0;
    float rP1 = (baseP1 + CeP1 + CoP1) * sc1, iP1 = -(SeP1 + SoP1) * sc1;
    float rT1 = (baseT1 + CeT1 + CoT1) * sc1, iT1 = -(SeT1 + SoT1) * sc1;
    size_t o = ((size_t)m * 181 + p) * 16 + bc;
    Gp[o] = make_float4(rP0 + rP1, iP0 + iP1, rT0 + rT1, iT0 + iT1);
    Gm[o] = make_float4(rP0 - rP1, iP0 - iP1, rT0 - rT1, iT0 - iT1);
  }
  // bin 360-m
  if (m >= 1 && m <= 179) {
    int m2 = 360 - m;
    float rP0 = (baseP0 + CeP0 - CoP0) * sc0, iP0 = (SeP0 - SoP0) * sc0;
    float rT0 = (baseT0 + CeT0 - CoT0) * sc0, iT0 = (SeT0 - SoT0) * sc0;
    float rP1 = (baseP1 + CeP1 - CoP1) * sc1, iP1 = (SeP1 - SoP1) * sc1;
    float rT1 = (baseT1 + CeT1 - CoT1) * sc1, iT1 = (SeT1 - SoT1) * sc1;
    size_t o = ((size_t)m2 * 181 + p) * 16 + bc;
    Gp[o] = make_float4(rP0 + rP1, iP0 + iP1, rT0 + rT1, iT0 + iT1);
    Gm[o] = make_float4(rP0 - rP1, iP0 - iP1, rT0 - rT1, iT0 - iT1);
  }
}

// ---------------------------------------------------------------------------
// Kernel 2: Legendre contraction + triangular PSD/cross-spectrum.
// Parity symmetry handled by the WRITER now (R7): pu0/pu1 select Gp/Gm by
// block-uniform parity of (l0+m) -> inner loop is 3 loads + 16 FMAs, no
// per-iteration fold, no cf, no j=180 special case (Gm[180]=0 by
// construction, Gp[180] pre-halved).
// Block: 256 thr = 16 bc x 4 j-lanes x 4 l-groups; 16 l x 2 m; grid 2208.
// sLg reverted to stride 20 (R6: stride-24+swizzle was neutral-to-negative;
// bank conflicts are ~6% of kernel cycles, not the bottleneck).
// Partials streamed to Spart (R3, no atomics).
// ---------------------------------------------------------------------------
__global__ __launch_bounds__(256, 8)
void leg_kernel(const float* __restrict__ leg,
                const float4* __restrict__ Gp,
                const float4* __restrict__ Gm,
                float4* __restrict__ Spart) {
  int bid = blockIdx.x;
  int lt = 0, acc = 0;
  while (bid >= acc + 8 * (lt + 1)) { acc += 8 * (lt + 1); ++lt; }
  const int l0 = lt * 16;
  const int m0 = (bid - acc) * 2;

  __shared__ float sLg[181][20];   // stride 20 floats (16B-aligned quads)
  const int tid = threadIdx.x;
  const int bc  = tid >> 4;        // 0..15  (consecutive bc lanes -> coalesced)
  const int jl  = (tid >> 2) & 3;  // 0..3   (xor 4/8 shuffle reduction)
  const int lpg = tid & 3;         // 0..3   (l-group: rows lpg*4 .. lpg*4+3)

  float racc[4][4];
#pragma unroll
  for (int r = 0; r < 4; ++r)
#pragma unroll
    for (int c = 0; c < 4; ++c) racc[r][c] = 0.f;

  for (int mi = 0; mi < 2; ++mi) {
    const int m = m0 + mi;
    if (m > 359) break;            // block-uniform
    if (mi) __syncthreads();
    // stage leg[l0..l0+15][m][0..180] transposed (coalesced global read)
    for (int idx = tid; idx < 16 * 181; idx += 256) {
      int lp = idx / 181, j = idx - lp * 181;
      int l = l0 + lp;
      sLg[j][lp] = (l <= 360) ? leg[((size_t)l * NLAT + m) * NLAT + j] : 0.f;
    }
    __syncthreads();

    // rows lpg*4 + {0,2} have parity (l0+m); rows {1,3} the opposite.
    // even parity -> symmetric part (Gp) feeds u0; odd -> Gm feeds u0.
    const bool pe = (((l0 + m) & 1) == 0);
    const float4* pu0 = (pe ? Gp : Gm) + (size_t)m * (181 * 16);
    const float4* pu1 = (pe ? Gm : Gp) + (size_t)m * (181 * 16);

    float ca[4][4];
#pragma unroll
    for (int r = 0; r < 4; ++r)
#pragma unroll
      for (int c = 0; c < 4; ++c) ca[r][c] = 0.f;

#pragma unroll 2
    for (int j = jl; j <= 180; j += 4) {
      float4 u0 = pu0[j * 16 + bc];
      float4 u1 = pu1[j * 16 + bc];
      float4 lg = *(const float4*)&sLg[j][lpg * 4];
      ca[0][0] += lg.x * u0.x; ca[0][1] += lg.x * u0.y;
      ca[0][2] += lg.x * u0.z; ca[0][3] += lg.x * u0.w;
      ca[1][0] += lg.y * u1.x; ca[1][1] += lg.y * u1.y;
      ca[1][2] += lg.y * u1.z; ca[1][3] += lg.y * u1.w;
      ca[2][0] += lg.z * u0.x; ca[2][1] += lg.z * u0.y;
      ca[2][2] += lg.z * u0.z; ca[2][3] += lg.z * u0.w;
      ca[3][0] += lg.w * u1.x; ca[3][1] += lg.w * u1.y;
      ca[3][2] += lg.w * u1.z; ca[3][3] += lg.w * u1.w;
    }

    // reduce across the 4 j-lanes (bits 2..3 of lane id)
#pragma unroll
    for (int r = 0; r < 4; ++r)
#pragma unroll
      for (int c = 0; c < 4; ++c) {
        ca[r][c] += __shfl_xor(ca[r][c], 4);
        ca[r][c] += __shfl_xor(ca[r][c], 8);
      }
    const float ef = (m == 0) ? 1.f : 2.f;
#pragma unroll
    for (int r = 0; r < 4; ++r) {
      float pr = ca[r][0], pi = ca[r][1], tr = ca[r][2], ti = ca[r][3];
      racc[r][0] += ef * (pr * pr + pi * pi);
      racc[r][1] += ef * (tr * tr + ti * ti);
      racc[r][2] += ef * (pr * tr + pi * ti);
      racc[r][3] += ef * (pr * ti - pi * tr);
    }
  }

  if (jl == 0) {
    // stream partials: Spart[bid][bc*16 + lrow] = (pp, tp, sr, si)
    float4* sp = Spart + (size_t)blockIdx.x * 256;
#pragma unroll
    for (int r = 0; r < 4; ++r) {
      int lrow = lpg * 4 + r;
      sp[bc * 16 + lrow] =
          make_float4(racc[r][0], racc[r][1], racc[r][2], racc[r][3]);
    }
  }
}

// ---------------------------------------------------------------------------
// Kernel 2b: sum per-block partials into S. 92 blocks (4 per l-tile, one
// thread per output element) + 4 independent accumulators (R4: fixed the
// serial-load-chain latency). nmb = 8*(lt+1) is always divisible by 4.
// ---------------------------------------------------------------------------
__global__ void red_kernel(const float* __restrict__ Spart,
                           float* __restrict__ S) {
  const int b    = blockIdx.x;            // 0..91
  const int lt   = b >> 2;                // 0..22
  const int base = 4 * lt * (lt + 1);     // prefix of 8*(i+1)
  const int nmb  = 8 * (lt + 1);          // m-blocks in this tile
  const int idx  = ((b & 3) << 8) | threadIdx.x;   // 0..1023

  const float* p = Spart + (size_t)base * 1024 + idx;
  float s0 = 0.f, s1 = 0.f, s2 = 0.f, s3 = 0.f;
  for (int mb = 0; mb < nmb; mb += 4) {
    s0 += p[(size_t)(mb + 0) * 1024];
    s1 += p[(size_t)(mb + 1) * 1024];
    s2 += p[(size_t)(mb + 2) * 1024];
    s3 += p[(size_t)(mb + 3) * 1024];
  }
  float s = (s0 + s1) + (s2 + s3);
  int bc = idx >> 6, lrow = (idx >> 2) & 15, c = idx & 3;
  int l = lt * 16 + lrow;
  if (l < 360) S[((size_t)bc * 360 + l) * 4 + c] = s;
}

// ---------------------------------------------------------------------------
// Kernel 3: final loss epilogue + reduction. One block.
// ---------------------------------------------------------------------------
__global__ void loss_kernel(const float* __restrict__ S,
                            const float* __restrict__ wts,
                            float* __restrict__ out) {
  const int tid = threadIdx.x;
  float acc = 0.f;
  for (int i = tid; i < 16 * 360; i += 256) {
    int bc = i / 360;
    const float* sp = S + (size_t)i * 4;
    float pp = sp[0] + EPSF;
    float tp = sp[1] + EPSF;
    float sr = sp[2], si = sp[3];
    float mag   = sqrtf(sr * sr + si * si);
    float denom = sqrtf(pp * tp + EPSF);
    float coh   = mag / (denom + EPSF);
    coh = fminf(fmaxf(coh, 0.f), 1.f);
    float sqp = sqrtf(pp), sqt = sqrtf(tp);
    float amp = (sqp - sqt) * (sqp - sqt);
    float dec = 2.f * fmaxf(pp, tp) * (1.f - coh);
    acc += (amp + dec) * wts[bc & 7];
  }
  __shared__ float red[4];
#pragma unroll
  for (int off = 32; off > 0; off >>= 1) acc += __shfl_xor(acc, off, 64);
  if ((tid & 63) == 0) red[tid >> 6] = acc;
  __syncthreads();
  if (tid == 0) {
    float loss = (red[0] + red[1] + red[2] + red[3]) / (360.f * 16.f);
    out[0] = isnan(loss) ? 1e6f : loss;
  }
}

// ---------------------------------------------------------------------------
extern "C" void kernel_launch(void* const* d_in, const int* in_sizes, int n_in,
                              void* d_out, int out_size, void* d_ws, size_t ws_size,
                              hipStream_t stream) {
  const float* pred = (const float*)d_in[0];   // [2,8,361,720]
  const float* targ = (const float*)d_in[1];   // [2,8,361,720]
  const float* wts  = (const float*)d_in[2];   // [8]
  const float* leg  = (const float*)d_in[3];   // [361,361,361]
  const float* wq   = (const float*)d_in[4];   // [361]
  float* out = (float*)d_out;

  float4* Gp    = (float4*)d_ws;                              // [360][181][16] float4
  float4* Gm    = Gp + (size_t)360 * 181 * 16;                // [360][181][16] float4
  float*  S     = (float*)(Gm + (size_t)360 * 181 * 16);      // [16][360][4]
  float*  Spart = S + (size_t)16 * 360 * 4;                   // [2208][1024]

  dft_kernel<<<16 * 181, 192, 0, stream>>>(pred, targ, wq, Gp, Gm);

  // 2208 = sum over 23 l-tiles of 8*(lt+1) two-m blocks
  leg_kernel<<<2208, 256, 0, stream>>>(leg, Gp, Gm, (float4*)Spart);

  red_kernel<<<92, 256, 0, stream>>>(Spart, S);

  loss_kernel<<<1, 256, 0, stream>>>(S, wts, out);
}